// Round 2
// baseline (678.713 us; speedup 1.0000x reference)
//
#include <hip/hip_runtime.h>
#include <cstdint>
#include <cmath>

// RandomPhongShader: exact reproduction of JAX threefry-partitionable RNG +
// XLA CPU float32 numerics (ErfInv32 Giles poly, EmitLog1p), fused shader.
//
// Round 2: replace OCML log(double) with inline f64 atanh-series log
// (decision-equivalent to correctly-rounded f64 log to ~1e-15 rel), make
// log1p Taylor branch select-based, force 3 waves/EU.
//
// Shapes: N=8,H=256,W=256,K=8, NB_SAMPLES=4. Pixels P = N*H*W = 524288.
// noise_h flat idx = s*4194304 + P*8 + k   (S,N,H,W,K)
// noise_a flat idx = s*4718592 + P*9 + j   (S,N,H,W,K+1)
// partitionable bits(i) = o0 ^ o1 of threefry2x32(key, (0, i))
// split(key(1)): kh = cipher((0,1),(0,0)), ka = cipher((0,1),(0,1))

#pragma clang fp contract(off)

#define NPIX 524288
#define STRIDE_H 4194304u
#define STRIDE_A 4718592u

__device__ __forceinline__ uint32_t rotl32(uint32_t v, int n) {
  return (v << n) | (v >> (32 - n));
}

__device__ __forceinline__ void tf2x32(uint32_t k0, uint32_t k1,
                                       uint32_t c0, uint32_t c1,
                                       uint32_t& o0, uint32_t& o1) {
  const uint32_t k2 = k0 ^ k1 ^ 0x1BD11BDAu;
  uint32_t x0 = c0 + k0, x1 = c1 + k1;
#define TFR(r) { x0 += x1; x1 = rotl32(x1, r); x1 ^= x0; }
  TFR(13) TFR(15) TFR(26) TFR(6)
  x0 += k1;  x1 += k2 + 1u;
  TFR(17) TFR(29) TFR(16) TFR(24)
  x0 += k2;  x1 += k0 + 2u;
  TFR(13) TFR(15) TFR(26) TFR(6)
  x0 += k0;  x1 += k1 + 3u;
  TFR(17) TFR(29) TFR(16) TFR(24)
  x0 += k1;  x1 += k2 + 4u;
  TFR(13) TFR(15) TFR(26) TFR(6)
  x0 += k2;  x1 += k0 + 5u;
#undef TFR
  o0 = x0; o1 = x1;
}

// Inline f64 log for z in (1e-7, 1.0001], z an exact f32 value. Rel error
// ~1e-15 vs correctly-rounded f64 log -> rounds to the same f32 as round 1's
// OCML path except with probability ~3e-8 per eval.
__device__ __forceinline__ double fast_log(double z) {
  uint64_t b = __double_as_longlong(z);
  int E = (int)(b >> 52) - 1023;
  double m = __longlong_as_double((b & 0x000FFFFFFFFFFFFFULL) |
                                  0x3FF0000000000000ULL);  // [1,2)
  const double SQRT2 = 1.4142135623730951;
  bool c = m > SQRT2;
  m = c ? m * 0.5 : m;   // exact
  E = c ? E + 1 : E;
  double s = (m - 1.0) / (m + 1.0);   // |s| <= 0.1716
  double u = s * s;                   // <= 0.02944
  double p = 1.0 / 19.0;
  p = fma(p, u, 1.0 / 17.0);
  p = fma(p, u, 1.0 / 15.0);
  p = fma(p, u, 1.0 / 13.0);
  p = fma(p, u, 1.0 / 11.0);
  p = fma(p, u, 1.0 / 9.0);
  p = fma(p, u, 1.0 / 7.0);
  p = fma(p, u, 1.0 / 5.0);
  p = fma(p, u, 1.0 / 3.0);
  p = fma(p, u, 1.0);
  double lm = (2.0 * s) * p;
  const double LN2_HI = 6.93147180369123816490e-01;  // 0x3FE62E42FEE00000
  const double LN2_LO = 1.90821492927058770002e-10;  // 0x3DEA39EF35793C76
  double e = (double)E;
  return fma(e, LN2_HI, fma(e, LN2_LO, lm));
}

// bits -> N(0,1) sample, replicating jax.random.normal f32 numerics:
//   f = bitcast(bits>>9 | 0x3f800000) - 1        in [0,1)
//   u = max(lo, f*(hi-lo) + lo), lo=-0x1.fffffep-1, (hi-lo) rounds to 2.0f
//   n = f32(sqrt(2)) * erfinv(u)   [XLA ErfInv32 Giles poly, no FMA]
//   log1p per XLA EmitLog1p: |t|<1e-4 ? (1 - t/2)*t : log(1+t)
__device__ __forceinline__ float bits_to_normal(uint32_t bits) {
  float f = __uint_as_float((bits >> 9) | 0x3f800000u) - 1.0f;  // exact
  const float lo = __uint_as_float(0xBF7FFFFFu);                // -0.99999994
  float v = __fadd_rn(__fmul_rn(f, 2.0f), lo);
  v = fmaxf(lo, v);
  float t = -__fmul_rn(v, v);  // -x*x (negation exact)
  // select-based log1p (both sides cheap now)
  float taylor = __fmul_rn(__fadd_rn(__fmul_rn(-0.5f, t), 1.0f), t);
  float lg = (float)fast_log((double)__fadd_rn(t, 1.0f));
  float l1p = (fabsf(t) < 1e-4f) ? taylor : lg;
  float w = -l1p;
  const bool lt = w < 5.0f;
  float ww = lt ? __fsub_rn(w, 2.5f) : __fsub_rn(__fsqrt_rn(w), 3.0f);
  float p  = lt ? 2.81022636e-08f : -0.000200214257f;
  p = __fadd_rn(lt ?  3.43273939e-07f :  0.000100950558f, __fmul_rn(p, ww));
  p = __fadd_rn(lt ? -3.5233877e-06f  :  0.00134934322f,  __fmul_rn(p, ww));
  p = __fadd_rn(lt ? -4.39150654e-06f : -0.00367342844f,  __fmul_rn(p, ww));
  p = __fadd_rn(lt ?  0.00021858087f  :  0.00573950773f,  __fmul_rn(p, ww));
  p = __fadd_rn(lt ? -0.00125372503f  : -0.0076224613f,   __fmul_rn(p, ww));
  p = __fadd_rn(lt ? -0.00417768164f  :  0.00943887047f,  __fmul_rn(p, ww));
  p = __fadd_rn(lt ?  0.246640727f    :  1.00167406f,     __fmul_rn(p, ww));
  p = __fadd_rn(lt ?  1.50140941f     :  2.83297682f,     __fmul_rn(p, ww));
  // f32(sqrt(2)) = 0x3FB504F3
  return __fmul_rn(__uint_as_float(0x3FB504F3u), __fmul_rn(p, v));
}

__global__ __launch_bounds__(256, 3) void RandomPhongShader_kernel(
    const float* __restrict__ colors,   // (P,8,3)
    const float* __restrict__ dists,    // (P,8)
    const float* __restrict__ zbuf,     // (P,8)
    const int*   __restrict__ p2f,      // (P,8)
    const float* __restrict__ bg,       // (3,)
    float* __restrict__ out)            // (P,4)
{
  const int P = blockIdx.x * 256 + threadIdx.x;
  if (P >= NPIX) return;

  // Derive kh/ka from root key (0,1) via fold-like split (partitionable).
  // All-constant inputs -> constant-folded by the compiler.
  uint32_t kh0, kh1, ka0, ka1;
  tf2x32(0u, 1u, 0u, 0u, kh0, kh1);
  tf2x32(0u, 1u, 0u, 1u, ka0, ka1);

  // ---- loads (vectorized) ----
  float dk[8], zk[8];
  int mk[8];
  {
    const float4* d4 = reinterpret_cast<const float4*>(dists + (size_t)P * 8);
    float4 a = d4[0], b = d4[1];
    dk[0]=a.x; dk[1]=a.y; dk[2]=a.z; dk[3]=a.w; dk[4]=b.x; dk[5]=b.y; dk[6]=b.z; dk[7]=b.w;
    const float4* z4 = reinterpret_cast<const float4*>(zbuf + (size_t)P * 8);
    float4 c = z4[0], e = z4[1];
    zk[0]=c.x; zk[1]=c.y; zk[2]=c.z; zk[3]=c.w; zk[4]=e.x; zk[5]=e.y; zk[6]=e.z; zk[7]=e.w;
    const int4* m4 = reinterpret_cast<const int4*>(p2f + (size_t)P * 8);
    int4 f = m4[0], g = m4[1];
    mk[0]=f.x; mk[1]=f.y; mk[2]=f.z; mk[3]=f.w; mk[4]=g.x; mk[5]=g.y; mk[6]=g.z; mk[7]=g.w;
  }

  // ---- prob_map via random_heaviside; alpha product (all values exact) ----
  const uint32_t baseH = (uint32_t)P * 8u;
  int li[8];           // index into log table = 4*prob_map
  float alpha = 1.0f;
  #pragma unroll
  for (int k = 0; k < 8; ++k) {
    const float x = -dk[k];
    int cnt = 0;
    #pragma unroll
    for (int s = 0; s < 4; ++s) {
      uint32_t o0, o1;
      tf2x32(kh0, kh1, 0u, (uint32_t)s * STRIDE_H + baseH + (uint32_t)k, o0, o1);
      float nz = bits_to_normal(o0 ^ o1);
      cnt += (__fadd_rn(x, __fmul_rn(0.1f, nz)) >= 0.0f) ? 1 : 0;
    }
    const float m = (mk[k] >= 0) ? 1.0f : 0.0f;
    const float pm = __fmul_rn(__fmul_rn((float)cnt, 0.25f), m);
    li[k] = (m != 0.0f) ? cnt : 0;
    alpha *= (1.0f - pm);  // products of {0,.25,.5,.75,1} complements: exact
  }

  // ---- z_inv, z_inv_max ----
  float zinv[8], zmax;
  #pragma unroll
  for (int k = 0; k < 8; ++k) {
    const float m = (mk[k] >= 0) ? 1.0f : 0.0f;
    float zi = __fmul_rn(__fdiv_rn(__fsub_rn(100.0f, zk[k]), 99.0f), m);
    zinv[k] = zi;
    zmax = (k == 0) ? zi : fmaxf(zmax, zi);
  }
  zmax = fmaxf(zmax, 1e-10f);  // jnp.clip(max, EPS)

  // log(EPS + prob): 5 possible inputs; EPS absorbed except prob=0.
  // Evaluated via the same inline log (constants, folded/uniform).
  const float lg0 = (float)fast_log((double)1e-10f);
  const float lg1 = (float)fast_log(0.25);
  const float lg2 = (float)fast_log(0.5);
  const float lg3 = (float)fast_log(0.75);

  float zm[9];
  #pragma unroll
  for (int k = 0; k < 8; ++k) {
    const int i = li[k];
    const float lg = (i == 0) ? lg0 : (i == 1) ? lg1 : (i == 2) ? lg2
                   : (i == 3) ? lg3 : 0.0f;
    zm[k] = __fadd_rn(lg, __fdiv_rn(__fsub_rn(zinv[k], zmax), 0.1f));
  }
  zm[8] = __fdiv_rn(__fsub_rn(1e-10f, zmax), 0.1f);  // bg_score

  // ---- random_argmax over K+1=9 channels, 4 samples ----
  float wgt[9] = {0.f,0.f,0.f,0.f,0.f,0.f,0.f,0.f,0.f};
  const uint32_t baseA = (uint32_t)P * 9u;
  #pragma unroll
  for (int s = 0; s < 4; ++s) {
    int am = 0;
    float best = 0.0f;
    #pragma unroll
    for (int j = 0; j < 9; ++j) {
      uint32_t o0, o1;
      tf2x32(ka0, ka1, 0u, (uint32_t)s * STRIDE_A + baseA + (uint32_t)j, o0, o1);
      float nz = bits_to_normal(o0 ^ o1);
      float v = __fadd_rn(zm[j], __fmul_rn(0.1f, nz));
      if (j == 0) { best = v; am = 0; }
      else if (v > best) { best = v; am = j; }  // strict > == first-max tiebreak
    }
    #pragma unroll
    for (int j = 0; j < 9; ++j) wgt[j] += (am == j) ? 0.25f : 0.0f;  // exact
  }

  // ---- epilogue: weighted colors + background, alpha channel ----
  float cc[24];
  {
    const float4* c4 = reinterpret_cast<const float4*>(colors + (size_t)P * 24);
    #pragma unroll
    for (int q = 0; q < 6; ++q) {
      float4 t = c4[q];
      cc[q*4+0]=t.x; cc[q*4+1]=t.y; cc[q*4+2]=t.z; cc[q*4+3]=t.w;
    }
  }
  float rgb[3];
  #pragma unroll
  for (int c = 0; c < 3; ++c) {
    float acc = 0.0f;
    #pragma unroll
    for (int k = 0; k < 8; ++k)
      acc = __fadd_rn(acc, __fmul_rn(wgt[k], cc[k * 3 + c]));
    rgb[c] = __fadd_rn(acc, __fmul_rn(wgt[8], bg[c]));
  }

  float4 o;
  o.x = rgb[0]; o.y = rgb[1]; o.z = rgb[2];
  o.w = __fsub_rn(1.0f, alpha);
  reinterpret_cast<float4*>(out)[P] = o;
}

extern "C" void kernel_launch(void* const* d_in, const int* in_sizes, int n_in,
                              void* d_out, int out_size, void* d_ws, size_t ws_size,
                              hipStream_t stream) {
  const float* colors = (const float*)d_in[0];
  const float* dists  = (const float*)d_in[1];
  const float* zbuf   = (const float*)d_in[2];
  const int*   p2f    = (const int*)d_in[3];
  const float* bg     = (const float*)d_in[4];
  float* out = (float*)d_out;
  dim3 grid(NPIX / 256), block(256);
  hipLaunchKernelGGL(RandomPhongShader_kernel, grid, block, 0, stream,
                     colors, dists, zbuf, p2f, bg, out);
}

// Round 3
// 358.184 us; speedup vs baseline: 1.8949x; 1.8949x over previous
//
#include <hip/hip_runtime.h>
#include <cstdint>
#include <cmath>

// RandomPhongShader: exact reproduction of JAX threefry-partitionable RNG +
// XLA CPU float32 numerics (ErfInv32 Giles poly, EmitLog1p), fused shader.
//
// Round 3: round-1 structure (NO waves/EU cap -- the (256,3) cap caused a
// 1 GB/dispatch scratch-spill catastrophe in round 2) + inline f64 log
// (decision-exact, ~30 insts vs ~100+ for OCML) with rcp+2xNewton division,
// and compile-time log table constants.
//
// Shapes: N=8,H=256,W=256,K=8, NB_SAMPLES=4. Pixels P = N*H*W = 524288.
// noise_h flat idx = s*4194304 + P*8 + k   (S,N,H,W,K)
// noise_a flat idx = s*4718592 + P*9 + j   (S,N,H,W,K+1)
// partitionable bits(i) = o0 ^ o1 of threefry2x32(key, (0, i))
// split(key(1)): kh = cipher((0,1),(0,0)), ka = cipher((0,1),(0,1))

#pragma clang fp contract(off)

#define NPIX 524288
#define STRIDE_H 4194304u
#define STRIDE_A 4718592u

__device__ __forceinline__ uint32_t rotl32(uint32_t v, int n) {
  return (v << n) | (v >> (32 - n));   // single v_alignbit_b32
}

__device__ __forceinline__ void tf2x32(uint32_t k0, uint32_t k1,
                                       uint32_t c0, uint32_t c1,
                                       uint32_t& o0, uint32_t& o1) {
  const uint32_t k2 = k0 ^ k1 ^ 0x1BD11BDAu;
  uint32_t x0 = c0 + k0, x1 = c1 + k1;
#define TFR(r) { x0 += x1; x1 = rotl32(x1, r); x1 ^= x0; }
  TFR(13) TFR(15) TFR(26) TFR(6)
  x0 += k1;  x1 += k2 + 1u;
  TFR(17) TFR(29) TFR(16) TFR(24)
  x0 += k2;  x1 += k0 + 2u;
  TFR(13) TFR(15) TFR(26) TFR(6)
  x0 += k0;  x1 += k1 + 3u;
  TFR(17) TFR(29) TFR(16) TFR(24)
  x0 += k1;  x1 += k2 + 4u;
  TFR(13) TFR(15) TFR(26) TFR(6)
  x0 += k2;  x1 += k0 + 5u;
#undef TFR
  o0 = x0; o1 = x1;
}

// Inline f64 log for z in (1e-7, 1.0001], z an exact f32 value.
// atanh series, |s|<=0.1716, truncation ~4e-18 rel; division via v_rcp_f64
// + 2 Newton steps (rel err ~2e-16). Total rel err ~5e-16 vs exact ->
// P(f32-rounds differently from correctly-rounded log) ~1.7e-8 per eval;
// ~0.6 one-ulp value events per run x ~1e-7 decision-flip prob each: safe.
__device__ __forceinline__ double fast_log(double z) {
  uint64_t b = __double_as_longlong(z);
  int E = (int)(b >> 52) - 1023;
  double m = __longlong_as_double((b & 0x000FFFFFFFFFFFFFULL) |
                                  0x3FF0000000000000ULL);  // [1,2)
  bool c = m > 1.4142135623730951;
  m = c ? m * 0.5 : m;   // exact
  E = c ? E + 1 : E;
  double d = m + 1.0;
  double r = __builtin_amdgcn_rcp(d);          // v_rcp_f64 approx
  r = fma(r, fma(-d, r, 1.0), r);              // Newton 1
  r = fma(r, fma(-d, r, 1.0), r);              // Newton 2 -> ~2e-16 rel
  double s = (m - 1.0) * r;                    // |s| <= 0.1716
  double u = s * s;
  double p = 1.0 / 19.0;
  p = fma(p, u, 1.0 / 17.0);
  p = fma(p, u, 1.0 / 15.0);
  p = fma(p, u, 1.0 / 13.0);
  p = fma(p, u, 1.0 / 11.0);
  p = fma(p, u, 1.0 / 9.0);
  p = fma(p, u, 1.0 / 7.0);
  p = fma(p, u, 1.0 / 5.0);
  p = fma(p, u, 1.0 / 3.0);
  p = fma(p, u, 1.0);
  double lm = (2.0 * s) * p;
  const double LN2_HI = 6.93147180369123816490e-01;  // 0x3FE62E42FEE00000
  const double LN2_LO = 1.90821492927058770002e-10;  // 0x3DEA39EF35793C76
  double e = (double)E;
  return fma(e, LN2_HI, fma(e, LN2_LO, lm));
}

// bits -> N(0,1) sample, replicating jax.random.normal f32 numerics:
//   f = bitcast(bits>>9 | 0x3f800000) - 1        in [0,1)
//   u = max(lo, f*(hi-lo) + lo), lo=-0x1.fffffep-1, (hi-lo) rounds to 2.0f
//   n = f32(sqrt(2)) * erfinv(u)   [XLA ErfInv32 Giles poly, no FMA]
//   log1p per XLA EmitLog1p: |t|<1e-4 ? (1 - t/2)*t : log(1+t)
__device__ __forceinline__ float bits_to_normal(uint32_t bits) {
  float f = __uint_as_float((bits >> 9) | 0x3f800000u) - 1.0f;  // exact
  const float lo = __uint_as_float(0xBF7FFFFFu);                // -0.99999994
  float v = __fadd_rn(__fmul_rn(f, 2.0f), lo);
  v = fmaxf(lo, v);
  float t = -__fmul_rn(v, v);  // -x*x (negation exact)
  float taylor = __fmul_rn(__fadd_rn(__fmul_rn(-0.5f, t), 1.0f), t);
  float lg = (float)fast_log((double)__fadd_rn(t, 1.0f));
  float l1p = (fabsf(t) < 1e-4f) ? taylor : lg;
  float w = -l1p;
  const bool lt = w < 5.0f;
  float ww = lt ? __fsub_rn(w, 2.5f) : __fsub_rn(__fsqrt_rn(w), 3.0f);
  float p  = lt ? 2.81022636e-08f : -0.000200214257f;
  p = __fadd_rn(lt ?  3.43273939e-07f :  0.000100950558f, __fmul_rn(p, ww));
  p = __fadd_rn(lt ? -3.5233877e-06f  :  0.00134934322f,  __fmul_rn(p, ww));
  p = __fadd_rn(lt ? -4.39150654e-06f : -0.00367342844f,  __fmul_rn(p, ww));
  p = __fadd_rn(lt ?  0.00021858087f  :  0.00573950773f,  __fmul_rn(p, ww));
  p = __fadd_rn(lt ? -0.00125372503f  : -0.0076224613f,   __fmul_rn(p, ww));
  p = __fadd_rn(lt ? -0.00417768164f  :  0.00943887047f,  __fmul_rn(p, ww));
  p = __fadd_rn(lt ?  0.246640727f    :  1.00167406f,     __fmul_rn(p, ww));
  p = __fadd_rn(lt ?  1.50140941f     :  2.83297682f,     __fmul_rn(p, ww));
  // f32(sqrt(2)) = 0x3FB504F3
  return __fmul_rn(__uint_as_float(0x3FB504F3u), __fmul_rn(p, v));
}

__global__ __launch_bounds__(256) void RandomPhongShader_kernel(
    const float* __restrict__ colors,   // (P,8,3)
    const float* __restrict__ dists,    // (P,8)
    const float* __restrict__ zbuf,     // (P,8)
    const int*   __restrict__ p2f,      // (P,8)
    const float* __restrict__ bg,       // (3,)
    float* __restrict__ out)            // (P,4)
{
  const int P = blockIdx.x * 256 + threadIdx.x;
  if (P >= NPIX) return;

  // Derive kh/ka from root key (0,1) via fold-like split (partitionable).
  // All-constant inputs -> constant-folded by the compiler.
  uint32_t kh0, kh1, ka0, ka1;
  tf2x32(0u, 1u, 0u, 0u, kh0, kh1);
  tf2x32(0u, 1u, 0u, 1u, ka0, ka1);

  // ---- loads (vectorized) ----
  float dk[8], zk[8];
  int mk[8];
  {
    const float4* d4 = reinterpret_cast<const float4*>(dists + (size_t)P * 8);
    float4 a = d4[0], b = d4[1];
    dk[0]=a.x; dk[1]=a.y; dk[2]=a.z; dk[3]=a.w; dk[4]=b.x; dk[5]=b.y; dk[6]=b.z; dk[7]=b.w;
    const float4* z4 = reinterpret_cast<const float4*>(zbuf + (size_t)P * 8);
    float4 c = z4[0], e = z4[1];
    zk[0]=c.x; zk[1]=c.y; zk[2]=c.z; zk[3]=c.w; zk[4]=e.x; zk[5]=e.y; zk[6]=e.z; zk[7]=e.w;
    const int4* m4 = reinterpret_cast<const int4*>(p2f + (size_t)P * 8);
    int4 f = m4[0], g = m4[1];
    mk[0]=f.x; mk[1]=f.y; mk[2]=f.z; mk[3]=f.w; mk[4]=g.x; mk[5]=g.y; mk[6]=g.z; mk[7]=g.w;
  }

  // ---- prob_map via random_heaviside; alpha product (all values exact) ----
  const uint32_t baseH = (uint32_t)P * 8u;
  int li[8];           // index into log table = 4*prob_map
  float alpha = 1.0f;
  #pragma unroll
  for (int k = 0; k < 8; ++k) {
    const float x = -dk[k];
    int cnt = 0;
    #pragma unroll
    for (int s = 0; s < 4; ++s) {
      uint32_t o0, o1;
      tf2x32(kh0, kh1, 0u, (uint32_t)s * STRIDE_H + baseH + (uint32_t)k, o0, o1);
      float nz = bits_to_normal(o0 ^ o1);
      cnt += (__fadd_rn(x, __fmul_rn(0.1f, nz)) >= 0.0f) ? 1 : 0;
    }
    const float m = (mk[k] >= 0) ? 1.0f : 0.0f;
    const float pm = __fmul_rn(__fmul_rn((float)cnt, 0.25f), m);
    li[k] = (m != 0.0f) ? cnt : 0;
    alpha *= (1.0f - pm);  // products of {0,.25,.5,.75,1} complements: exact
  }

  // ---- z_inv, z_inv_max ----
  float zinv[8], zmax;
  #pragma unroll
  for (int k = 0; k < 8; ++k) {
    const float m = (mk[k] >= 0) ? 1.0f : 0.0f;
    float zi = __fmul_rn(__fdiv_rn(__fsub_rn(100.0f, zk[k]), 99.0f), m);
    zinv[k] = zi;
    zmax = (k == 0) ? zi : fmaxf(zmax, zi);
  }
  zmax = fmaxf(zmax, 1e-10f);  // jnp.clip(max, EPS)

  // log(EPS + prob): 5 possible inputs; EPS absorbed (in f32) except prob=0.
  // Compile-time constants == f32(correctly-rounded f64 log) as validated
  // in rounds 1-2 (checked: lg0 candidates agree in f32).
  const float lg0 = (float)-23.025850916589025;  // log(1e-10f)
  const float lg1 = (float)-1.3862943611198906;  // log(0.25)
  const float lg2 = (float)-0.6931471805599453;  // log(0.5)
  const float lg3 = (float)-0.2876820724517809;  // log(0.75)

  float zm[9];
  #pragma unroll
  for (int k = 0; k < 8; ++k) {
    const int i = li[k];
    const float lg = (i == 0) ? lg0 : (i == 1) ? lg1 : (i == 2) ? lg2
                   : (i == 3) ? lg3 : 0.0f;
    zm[k] = __fadd_rn(lg, __fdiv_rn(__fsub_rn(zinv[k], zmax), 0.1f));
  }
  zm[8] = __fdiv_rn(__fsub_rn(1e-10f, zmax), 0.1f);  // bg_score

  // ---- random_argmax over K+1=9 channels, 4 samples ----
  float wgt[9] = {0.f,0.f,0.f,0.f,0.f,0.f,0.f,0.f,0.f};
  const uint32_t baseA = (uint32_t)P * 9u;
  #pragma unroll
  for (int s = 0; s < 4; ++s) {
    int am = 0;
    float best = 0.0f;
    #pragma unroll
    for (int j = 0; j < 9; ++j) {
      uint32_t o0, o1;
      tf2x32(ka0, ka1, 0u, (uint32_t)s * STRIDE_A + baseA + (uint32_t)j, o0, o1);
      float nz = bits_to_normal(o0 ^ o1);
      float v = __fadd_rn(zm[j], __fmul_rn(0.1f, nz));
      if (j == 0) { best = v; am = 0; }
      else if (v > best) { best = v; am = j; }  // strict > == first-max tiebreak
    }
    #pragma unroll
    for (int j = 0; j < 9; ++j) wgt[j] += (am == j) ? 0.25f : 0.0f;  // exact
  }

  // ---- epilogue: weighted colors + background, alpha channel ----
  float cc[24];
  {
    const float4* c4 = reinterpret_cast<const float4*>(colors + (size_t)P * 24);
    #pragma unroll
    for (int q = 0; q < 6; ++q) {
      float4 t = c4[q];
      cc[q*4+0]=t.x; cc[q*4+1]=t.y; cc[q*4+2]=t.z; cc[q*4+3]=t.w;
    }
  }
  float rgb[3];
  #pragma unroll
  for (int c = 0; c < 3; ++c) {
    float acc = 0.0f;
    #pragma unroll
    for (int k = 0; k < 8; ++k)
      acc = __fadd_rn(acc, __fmul_rn(wgt[k], cc[k * 3 + c]));
    rgb[c] = __fadd_rn(acc, __fmul_rn(wgt[8], bg[c]));
  }

  float4 o;
  o.x = rgb[0]; o.y = rgb[1]; o.z = rgb[2];
  o.w = __fsub_rn(1.0f, alpha);
  reinterpret_cast<float4*>(out)[P] = o;
}

extern "C" void kernel_launch(void* const* d_in, const int* in_sizes, int n_in,
                              void* d_out, int out_size, void* d_ws, size_t ws_size,
                              hipStream_t stream) {
  const float* colors = (const float*)d_in[0];
  const float* dists  = (const float*)d_in[1];
  const float* zbuf   = (const float*)d_in[2];
  const int*   p2f    = (const int*)d_in[3];
  const float* bg     = (const float*)d_in[4];
  float* out = (float*)d_out;
  dim3 grid(NPIX / 256), block(256);
  hipLaunchKernelGGL(RandomPhongShader_kernel, grid, block, 0, stream,
                     colors, dists, zbuf, p2f, bg, out);
}

// Round 4
// 227.365 us; speedup vs baseline: 2.9851x; 1.5754x over previous
//
#include <hip/hip_runtime.h>
#include <cstdint>
#include <cmath>

// RandomPhongShader: exact reproduction of JAX threefry-partitionable RNG +
// XLA CPU float32 numerics (ErfInv32 Giles poly, EmitLog1p), fused shader.
//
// Round 4: (a) branchy erfinv -- lt-coeff chain always (pure literal VOP2
// mul/add), gt-chain+sqrt only under wave-uniform ballot(w>=5) (0.34% of
// draws, ~20% of waves); (b) fast_log trimmed to 1 Newton + 6-term series
// (rel err ~6e-11, expected decision flips ~3e-4); (c) sample loops rolled
// (#pragma unroll 1) with k/j unrolled inside to shrink live sets -> higher
// occupancy; argmax weights packed in one u32. NO waves/EU cap (round-2
// lesson: forced caps + wide code = 1 GB spill catastrophe).
//
// Shapes: N=8,H=256,W=256,K=8, NB_SAMPLES=4. Pixels P = N*H*W = 524288.
// noise_h flat idx = s*4194304 + P*8 + k   (S,N,H,W,K)
// noise_a flat idx = s*4718592 + P*9 + j   (S,N,H,W,K+1)
// partitionable bits(i) = o0 ^ o1 of threefry2x32(key, (0, i))
// split(key(1)): kh = cipher((0,1),(0,0)), ka = cipher((0,1),(0,1))

#pragma clang fp contract(off)

#define NPIX 524288
#define STRIDE_H 4194304u
#define STRIDE_A 4718592u

__device__ __forceinline__ uint32_t rotl32(uint32_t v, int n) {
  return (v << n) | (v >> (32 - n));   // single v_alignbit_b32
}

__device__ __forceinline__ void tf2x32(uint32_t k0, uint32_t k1,
                                       uint32_t c0, uint32_t c1,
                                       uint32_t& o0, uint32_t& o1) {
  const uint32_t k2 = k0 ^ k1 ^ 0x1BD11BDAu;
  uint32_t x0 = c0 + k0, x1 = c1 + k1;
#define TFR(r) { x0 += x1; x1 = rotl32(x1, r); x1 ^= x0; }
  TFR(13) TFR(15) TFR(26) TFR(6)
  x0 += k1;  x1 += k2 + 1u;
  TFR(17) TFR(29) TFR(16) TFR(24)
  x0 += k2;  x1 += k0 + 2u;
  TFR(13) TFR(15) TFR(26) TFR(6)
  x0 += k0;  x1 += k1 + 3u;
  TFR(17) TFR(29) TFR(16) TFR(24)
  x0 += k1;  x1 += k2 + 4u;
  TFR(13) TFR(15) TFR(26) TFR(6)
  x0 += k2;  x1 += k0 + 5u;
#undef TFR
  o0 = x0; o1 = x1;
}

// Inline f64 log for z in (1e-7, 1.0001], z an exact f32 value.
// atanh series (6 terms, |s|<=0.1716 -> trunc ~6e-11 rel), division via
// v_rcp_f64 + 1 Newton (seed ~2^-27 -> ~2^-54). Total rel err ~6e-11 ->
// ~36k one-ulp f32 log events per 35.7M draws x ~8e-9 decision-flip prob
// each = ~3e-4 expected flips: safe.
__device__ __forceinline__ double fast_log(double z) {
  uint64_t b = __double_as_longlong(z);
  int E = (int)(b >> 52) - 1023;
  double m = __longlong_as_double((b & 0x000FFFFFFFFFFFFFULL) |
                                  0x3FF0000000000000ULL);  // [1,2)
  bool c = m > 1.4142135623730951;
  m = c ? m * 0.5 : m;   // exact
  E = c ? E + 1 : E;
  double d = m + 1.0;
  double r = __builtin_amdgcn_rcp(d);          // v_rcp_f64 approx (~2^-27)
  r = fma(r, fma(-d, r, 1.0), r);              // 1 Newton -> ~2^-54
  double s = (m - 1.0) * r;                    // |s| <= 0.1716
  double u = s * s;                            // <= 0.02944
  double p = 1.0 / 11.0;
  p = fma(p, u, 1.0 / 9.0);
  p = fma(p, u, 1.0 / 7.0);
  p = fma(p, u, 1.0 / 5.0);
  p = fma(p, u, 1.0 / 3.0);
  p = fma(p, u, 1.0);
  double lm = (2.0 * s) * p;
  const double LN2_HI = 6.93147180369123816490e-01;  // 0x3FE62E42FEE00000
  const double LN2_LO = 1.90821492927058770002e-10;  // 0x3DEA39EF35793C76
  double e = (double)E;
  return fma(e, LN2_HI, fma(e, LN2_LO, lm));
}

// bits -> N(0,1) sample, replicating jax.random.normal f32 numerics:
//   f = bitcast(bits>>9 | 0x3f800000) - 1        in [0,1)
//   u = max(lo, f*(hi-lo) + lo), lo=-0x1.fffffep-1, (hi-lo) rounds to 2.0f
//   n = f32(sqrt(2)) * erfinv(u)   [XLA ErfInv32 Giles poly, no FMA]
//   log1p per XLA EmitLog1p: |t|<1e-4 ? (1 - t/2)*t : log(1+t)
// erfinv branch: lt path (w<5) computed always; gt path only when some lane
// in the wave needs it (|v|>0.99663, 0.34% of draws). Per-lane op sequence
// identical to the select version -> bit-identical results.
__device__ __forceinline__ float bits_to_normal(uint32_t bits) {
  float f = __uint_as_float((bits >> 9) | 0x3f800000u) - 1.0f;  // exact
  const float lo = __uint_as_float(0xBF7FFFFFu);                // -0.99999994
  float v = __fadd_rn(__fmul_rn(f, 2.0f), lo);
  v = fmaxf(lo, v);
  float t = -__fmul_rn(v, v);  // -x*x (negation exact)
  float taylor = __fmul_rn(__fadd_rn(__fmul_rn(-0.5f, t), 1.0f), t);
  float lg = (float)fast_log((double)__fadd_rn(t, 1.0f));
  float l1p = (fabsf(t) < 1e-4f) ? taylor : lg;
  float w = -l1p;
  // common chain (w < 2.5 centering), literal-operand mul/add only
  float ww = __fsub_rn(w, 2.5f);
  float p = 2.81022636e-08f;
  p = __fadd_rn( 3.43273939e-07f, __fmul_rn(p, ww));
  p = __fadd_rn(-3.5233877e-06f , __fmul_rn(p, ww));
  p = __fadd_rn(-4.39150654e-06f, __fmul_rn(p, ww));
  p = __fadd_rn( 0.00021858087f , __fmul_rn(p, ww));
  p = __fadd_rn(-0.00125372503f , __fmul_rn(p, ww));
  p = __fadd_rn(-0.00417768164f , __fmul_rn(p, ww));
  p = __fadd_rn( 0.246640727f   , __fmul_rn(p, ww));
  p = __fadd_rn( 1.50140941f    , __fmul_rn(p, ww));
  if (__builtin_expect(__ballot(w >= 5.0f) != 0ull, 0)) {
    float w2 = __fsub_rn(__fsqrt_rn(w), 3.0f);
    float q = -0.000200214257f;
    q = __fadd_rn( 0.000100950558f, __fmul_rn(q, w2));
    q = __fadd_rn( 0.00134934322f , __fmul_rn(q, w2));
    q = __fadd_rn(-0.00367342844f , __fmul_rn(q, w2));
    q = __fadd_rn( 0.00573950773f , __fmul_rn(q, w2));
    q = __fadd_rn(-0.0076224613f  , __fmul_rn(q, w2));
    q = __fadd_rn( 0.00943887047f , __fmul_rn(q, w2));
    q = __fadd_rn( 1.00167406f    , __fmul_rn(q, w2));
    q = __fadd_rn( 2.83297682f    , __fmul_rn(q, w2));
    p = (w < 5.0f) ? p : q;
  }
  // f32(sqrt(2)) = 0x3FB504F3
  return __fmul_rn(__uint_as_float(0x3FB504F3u), __fmul_rn(p, v));
}

__global__ __launch_bounds__(256) void RandomPhongShader_kernel(
    const float* __restrict__ colors,   // (P,8,3)
    const float* __restrict__ dists,    // (P,8)
    const float* __restrict__ zbuf,     // (P,8)
    const int*   __restrict__ p2f,      // (P,8)
    const float* __restrict__ bg,       // (3,)
    float* __restrict__ out)            // (P,4)
{
  const int P = blockIdx.x * 256 + threadIdx.x;
  if (P >= NPIX) return;

  // Derive kh/ka from root key (0,1) via fold-like split (partitionable).
  // All-constant inputs -> constant-folded by the compiler.
  uint32_t kh0, kh1, ka0, ka1;
  tf2x32(0u, 1u, 0u, 0u, kh0, kh1);
  tf2x32(0u, 1u, 0u, 1u, ka0, ka1);

  // ---- phase 1: heaviside counts (needs dists, p2f later) ----
  float dk[8];
  int mk[8];
  {
    const float4* d4 = reinterpret_cast<const float4*>(dists + (size_t)P * 8);
    float4 a = d4[0], b = d4[1];
    dk[0]=a.x; dk[1]=a.y; dk[2]=a.z; dk[3]=a.w; dk[4]=b.x; dk[5]=b.y; dk[6]=b.z; dk[7]=b.w;
    const int4* m4 = reinterpret_cast<const int4*>(p2f + (size_t)P * 8);
    int4 f = m4[0], g = m4[1];
    mk[0]=f.x; mk[1]=f.y; mk[2]=f.z; mk[3]=f.w; mk[4]=g.x; mk[5]=g.y; mk[6]=g.z; mk[7]=g.w;
  }

  int cnt[8] = {0,0,0,0,0,0,0,0};
  uint32_t cH = (uint32_t)P * 8u;
  #pragma unroll 1
  for (int s = 0; s < 4; ++s) {
    #pragma unroll
    for (int k = 0; k < 8; ++k) {
      uint32_t o0, o1;
      tf2x32(kh0, kh1, 0u, cH + (uint32_t)k, o0, o1);
      float nz = bits_to_normal(o0 ^ o1);
      cnt[k] += (__fadd_rn(-dk[k], __fmul_rn(0.1f, nz)) >= 0.0f) ? 1 : 0;
    }
    cH += STRIDE_H;
  }

  // ---- phase 2: alpha, z_inv, z_map (frees dk/zk/mk/cnt afterwards) ----
  float zk[8];
  {
    const float4* z4 = reinterpret_cast<const float4*>(zbuf + (size_t)P * 8);
    float4 c = z4[0], e = z4[1];
    zk[0]=c.x; zk[1]=c.y; zk[2]=c.z; zk[3]=c.w; zk[4]=e.x; zk[5]=e.y; zk[6]=e.z; zk[7]=e.w;
  }
  float zinv[8], zmax;
  #pragma unroll
  for (int k = 0; k < 8; ++k) {
    const float m = (mk[k] >= 0) ? 1.0f : 0.0f;
    float zi = __fmul_rn(__fdiv_rn(__fsub_rn(100.0f, zk[k]), 99.0f), m);
    zinv[k] = zi;
    zmax = (k == 0) ? zi : fmaxf(zmax, zi);
  }
  zmax = fmaxf(zmax, 1e-10f);  // jnp.clip(max, EPS)

  // log(EPS + prob): 5 possible inputs; EPS absorbed (in f32) except prob=0.
  const float lg0 = (float)-23.025850916589025;  // log(1e-10f)
  const float lg1 = (float)-1.3862943611198906;  // log(0.25)
  const float lg2 = (float)-0.6931471805599453;  // log(0.5)
  const float lg3 = (float)-0.2876820724517809;  // log(0.75)

  float alpha = 1.0f;
  float zm[9];
  #pragma unroll
  for (int k = 0; k < 8; ++k) {
    const float m = (mk[k] >= 0) ? 1.0f : 0.0f;
    const float pm = __fmul_rn(__fmul_rn((float)cnt[k], 0.25f), m);
    alpha *= (1.0f - pm);  // products of {0,.25,.5,.75,1} complements: exact
    const int i = (mk[k] >= 0) ? cnt[k] : 0;
    const float lg = (i == 0) ? lg0 : (i == 1) ? lg1 : (i == 2) ? lg2
                   : (i == 3) ? lg3 : 0.0f;
    zm[k] = __fadd_rn(lg, __fdiv_rn(__fsub_rn(zinv[k], zmax), 0.1f));
  }
  zm[8] = __fdiv_rn(__fsub_rn(1e-10f, zmax), 0.1f);  // bg_score

  // ---- phase 3: random_argmax, 4 samples x 9 channels, packed result ----
  uint32_t amPack = 0;  // 9 x 3-bit counters (counts <= 4)
  uint32_t cA = (uint32_t)P * 9u;
  #pragma unroll 1
  for (int s = 0; s < 4; ++s) {
    int am = 0;
    float best = 0.0f;
    #pragma unroll
    for (int j = 0; j < 9; ++j) {
      uint32_t o0, o1;
      tf2x32(ka0, ka1, 0u, cA + (uint32_t)j, o0, o1);
      float nz = bits_to_normal(o0 ^ o1);
      float v = __fadd_rn(zm[j], __fmul_rn(0.1f, nz));
      if (j == 0) { best = v; am = 0; }
      else { bool g = v > best; best = g ? v : best; am = g ? j : am; }
    }
    amPack += 1u << (3 * am);
    cA += STRIDE_A;
  }

  // ---- phase 4: epilogue ----
  float wgt[9];
  #pragma unroll
  for (int j = 0; j < 9; ++j)
    wgt[j] = __fmul_rn(0.25f, (float)((amPack >> (3 * j)) & 7u));  // exact

  float cc[24];
  {
    const float4* c4 = reinterpret_cast<const float4*>(colors + (size_t)P * 24);
    #pragma unroll
    for (int q = 0; q < 6; ++q) {
      float4 t = c4[q];
      cc[q*4+0]=t.x; cc[q*4+1]=t.y; cc[q*4+2]=t.z; cc[q*4+3]=t.w;
    }
  }
  float rgb[3];
  #pragma unroll
  for (int c = 0; c < 3; ++c) {
    float acc = 0.0f;
    #pragma unroll
    for (int k = 0; k < 8; ++k)
      acc = __fadd_rn(acc, __fmul_rn(wgt[k], cc[k * 3 + c]));
    rgb[c] = __fadd_rn(acc, __fmul_rn(wgt[8], bg[c]));
  }

  float4 o;
  o.x = rgb[0]; o.y = rgb[1]; o.z = rgb[2];
  o.w = __fsub_rn(1.0f, alpha);
  reinterpret_cast<float4*>(out)[P] = o;
}

extern "C" void kernel_launch(void* const* d_in, const int* in_sizes, int n_in,
                              void* d_out, int out_size, void* d_ws, size_t ws_size,
                              hipStream_t stream) {
  const float* colors = (const float*)d_in[0];
  const float* dists  = (const float*)d_in[1];
  const float* zbuf   = (const float*)d_in[2];
  const int*   p2f    = (const int*)d_in[3];
  const float* bg     = (const float*)d_in[4];
  float* out = (float*)d_out;
  dim3 grid(NPIX / 256), block(256);
  hipLaunchKernelGGL(RandomPhongShader_kernel, grid, block, 0, stream,
                     colors, dists, zbuf, p2f, bg, out);
}

// Round 5
// 196.000 us; speedup vs baseline: 3.4628x; 1.1600x over previous
//
#include <hip/hip_runtime.h>
#include <cstdint>
#include <cmath>

// RandomPhongShader: exact reproduction of JAX threefry-partitionable RNG +
// XLA CPU float32 numerics, fused shader.
//
// Round 5: approximate fast paths + exact fallback under conservative margin.
//  - Heaviside: decision inverted to v-space (v >= erf(10*d/sqrt2)); per draw
//    only threefry + uniform extract + banded compare. Band 3e-4 (~150x over
//    the ~2e-6 real boundary uncertainty); flagged lanes re-run the exact
//    chain (round-3/4-validated) and correct the count.
//  - Argmax: hot chain uses v_log_f32 + FMA-contracted Giles poly (v,t,u kept
//    bit-exact: tail slope dnz/dv ~3e5 amplifies v-errors). Band 5e-5 on the
//    running-max comparisons; flagged lanes redo the whole 9-draw sample with
//    the exact chain (zm staged in LDS for dynamic indexing w/o scratch).
//  - Counts packed in u32 nibbles; NO waves/EU cap (round-2 spill lesson).
//
// Shapes: N=8,H=256,W=256,K=8, NB_SAMPLES=4. Pixels P = N*H*W = 524288.
// partitionable bits(i) = o0 ^ o1 of threefry2x32(key, (0, i))
// split(key(1)): kh = cipher((0,1),(0,0)), ka = cipher((0,1),(0,1))

#pragma clang fp contract(off)

#define NPIX 524288
#define STRIDE_H 4194304u
#define STRIDE_A 4718592u

#define BAND_H 3e-4f
#define BAND_A 5e-5f

__device__ __forceinline__ uint32_t rotl32(uint32_t v, int n) {
  return (v << n) | (v >> (32 - n));   // v_alignbit_b32
}

__device__ __forceinline__ void tf2x32(uint32_t k0, uint32_t k1,
                                       uint32_t c0, uint32_t c1,
                                       uint32_t& o0, uint32_t& o1) {
  const uint32_t k2 = k0 ^ k1 ^ 0x1BD11BDAu;
  uint32_t x0 = c0 + k0, x1 = c1 + k1;
#define TFR(r) { x0 += x1; x1 = rotl32(x1, r); x1 ^= x0; }
  TFR(13) TFR(15) TFR(26) TFR(6)
  x0 += k1;  x1 += k2 + 1u;
  TFR(17) TFR(29) TFR(16) TFR(24)
  x0 += k2;  x1 += k0 + 2u;
  TFR(13) TFR(15) TFR(26) TFR(6)
  x0 += k0;  x1 += k1 + 3u;
  TFR(17) TFR(29) TFR(16) TFR(24)
  x0 += k1;  x1 += k2 + 4u;
  TFR(13) TFR(15) TFR(26) TFR(6)
  x0 += k2;  x1 += k0 + 5u;
#undef TFR
  o0 = x0; o1 = x1;
}

// ---- exact path (cold): round-3/4-validated numerics ----
__device__ __forceinline__ double fast_log(double z) {
  uint64_t b = __double_as_longlong(z);
  int E = (int)(b >> 52) - 1023;
  double m = __longlong_as_double((b & 0x000FFFFFFFFFFFFFULL) |
                                  0x3FF0000000000000ULL);  // [1,2)
  bool c = m > 1.4142135623730951;
  m = c ? m * 0.5 : m;   // exact
  E = c ? E + 1 : E;
  double d = m + 1.0;
  double r = __builtin_amdgcn_rcp(d);
  r = fma(r, fma(-d, r, 1.0), r);              // Newton 1
  r = fma(r, fma(-d, r, 1.0), r);              // Newton 2 -> ~2e-16 rel
  double s = (m - 1.0) * r;
  double u = s * s;
  double p = 1.0 / 19.0;
  p = fma(p, u, 1.0 / 17.0);
  p = fma(p, u, 1.0 / 15.0);
  p = fma(p, u, 1.0 / 13.0);
  p = fma(p, u, 1.0 / 11.0);
  p = fma(p, u, 1.0 / 9.0);
  p = fma(p, u, 1.0 / 7.0);
  p = fma(p, u, 1.0 / 5.0);
  p = fma(p, u, 1.0 / 3.0);
  p = fma(p, u, 1.0);
  double lm = (2.0 * s) * p;
  const double LN2_HI = 6.93147180369123816490e-01;
  const double LN2_LO = 1.90821492927058770002e-10;
  double e = (double)E;
  return fma(e, LN2_HI, fma(e, LN2_LO, lm));
}

__device__ __forceinline__ float normal_exact(uint32_t bits) {
  float f = __uint_as_float((bits >> 9) | 0x3f800000u) - 1.0f;  // exact
  const float lo = __uint_as_float(0xBF7FFFFFu);
  float v = __fadd_rn(__fmul_rn(f, 2.0f), lo);
  v = fmaxf(lo, v);
  float t = -__fmul_rn(v, v);
  float taylor = __fmul_rn(__fadd_rn(__fmul_rn(-0.5f, t), 1.0f), t);
  float lg = (float)fast_log((double)__fadd_rn(t, 1.0f));
  float l1p = (fabsf(t) < 1e-4f) ? taylor : lg;
  float w = -l1p;
  const bool lt = w < 5.0f;
  float ww = lt ? __fsub_rn(w, 2.5f) : __fsub_rn(__fsqrt_rn(w), 3.0f);
  float p  = lt ? 2.81022636e-08f : -0.000200214257f;
  p = __fadd_rn(lt ?  3.43273939e-07f :  0.000100950558f, __fmul_rn(p, ww));
  p = __fadd_rn(lt ? -3.5233877e-06f  :  0.00134934322f,  __fmul_rn(p, ww));
  p = __fadd_rn(lt ? -4.39150654e-06f : -0.00367342844f,  __fmul_rn(p, ww));
  p = __fadd_rn(lt ?  0.00021858087f  :  0.00573950773f,  __fmul_rn(p, ww));
  p = __fadd_rn(lt ? -0.00125372503f  : -0.0076224613f,   __fmul_rn(p, ww));
  p = __fadd_rn(lt ? -0.00417768164f  :  0.00943887047f,  __fmul_rn(p, ww));
  p = __fadd_rn(lt ?  0.246640727f    :  1.00167406f,     __fmul_rn(p, ww));
  p = __fadd_rn(lt ?  1.50140941f     :  2.83297682f,     __fmul_rn(p, ww));
  return __fmul_rn(__uint_as_float(0x3FB504F3u), __fmul_rn(p, v));
}

// ---- approx path (hot): v,t,u bit-exact; log/poly approximated.
// |nz_fast - nz_exact| <= ~2e-5 absolute (log rel err ~5e-7 * w<=16 * |p'|<=1,
// + FMA-vs-mul/add reordering ~5e-6). BAND_A/BAND_H sized >=12x over this.
__device__ __forceinline__ float normal_fast(uint32_t bits) {
  float f = __uint_as_float((bits >> 9) | 0x3f800000u) - 1.0f;
  const float lo = __uint_as_float(0xBF7FFFFFu);
  float v = __fadd_rn(__fmul_rn(f, 2.0f), lo);
  v = fmaxf(lo, v);
  float t = -__fmul_rn(v, v);
  float u = __fadd_rn(t, 1.0f);
  float wlog = __fmul_rn(-0.6931471805599453f, __builtin_amdgcn_logf(u));
  float wtay = __fmul_rn(__fmaf_rn(0.5f, t, -1.0f), t);   // = -(1 - t/2)*t
  float w = (fabsf(t) < 1e-4f) ? wtay : wlog;
  float ww = w - 2.5f;
  float p = 2.81022636e-08f;
  p = __fmaf_rn(p, ww,  3.43273939e-07f);
  p = __fmaf_rn(p, ww, -3.5233877e-06f);
  p = __fmaf_rn(p, ww, -4.39150654e-06f);
  p = __fmaf_rn(p, ww,  0.00021858087f);
  p = __fmaf_rn(p, ww, -0.00125372503f);
  p = __fmaf_rn(p, ww, -0.00417768164f);
  p = __fmaf_rn(p, ww,  0.246640727f);
  p = __fmaf_rn(p, ww,  1.50140941f);
  if (__builtin_expect(__ballot(w >= 5.0f) != 0ull, 0)) {
    float w2 = __builtin_amdgcn_sqrtf(w) - 3.0f;
    float q = -0.000200214257f;
    q = __fmaf_rn(q, w2,  0.000100950558f);
    q = __fmaf_rn(q, w2,  0.00134934322f);
    q = __fmaf_rn(q, w2, -0.00367342844f);
    q = __fmaf_rn(q, w2,  0.00573950773f);
    q = __fmaf_rn(q, w2, -0.0076224613f);
    q = __fmaf_rn(q, w2,  0.00943887047f);
    q = __fmaf_rn(q, w2,  1.00167406f);
    q = __fmaf_rn(q, w2,  2.83297682f);
    p = (w < 5.0f) ? p : q;
  }
  return __fmul_rn(1.4142135f, __fmul_rn(p, v));
}

__global__ __launch_bounds__(256) void RandomPhongShader_kernel(
    const float* __restrict__ colors,   // (P,8,3)
    const float* __restrict__ dists,    // (P,8)
    const float* __restrict__ zbuf,     // (P,8)
    const int*   __restrict__ p2f,      // (P,8)
    const float* __restrict__ bg,       // (3,)
    float* __restrict__ out)            // (P,4)
{
  __shared__ float zmS[256][9];   // staged z_map for dynamic-index cold loop
  const int tid = threadIdx.x;
  const int P = blockIdx.x * 256 + tid;
  if (P >= NPIX) return;

  // keys: fold-like split of root key (0,1) -- constant-folded
  uint32_t kh0, kh1, ka0, ka1;
  tf2x32(0u, 1u, 0u, 0u, kh0, kh1);
  tf2x32(0u, 1u, 0u, 1u, ka0, ka1);

  // ---- phase 0: per-(pixel,k) decision thresholds in v-space ----
  // m = -d + 0.1*nz >= 0  <=>  nz >= 10*d  <=>  v >= erf(10*d/sqrt2)
  // erf via A&S 7.1.26 (|err|<=1.5e-7); band BAND_H covers everything.
  float vs[8];
  {
    const float4* d4 = reinterpret_cast<const float4*>(dists + (size_t)P * 8);
    float4 a = d4[0], b = d4[1];
    float dk[8] = {a.x,a.y,a.z,a.w,b.x,b.y,b.z,b.w};
    #pragma unroll
    for (int k = 0; k < 8; ++k) {
      float y = fabsf(dk[k]) * 7.0710678f;           // |10*d|/sqrt2
      float tt = __builtin_amdgcn_rcpf(__fmaf_rn(0.3275911f, y, 1.0f));
      float ex = __builtin_amdgcn_exp2f(__fmul_rn(-1.4426951f, y * y));
      float pp = 1.061405429f;
      pp = __fmaf_rn(pp, tt, -1.453152027f);
      pp = __fmaf_rn(pp, tt,  1.421413741f);
      pp = __fmaf_rn(pp, tt, -0.284496736f);
      pp = __fmaf_rn(pp, tt,  0.254829592f);
      float er = __fmaf_rn(-pp * tt, ex, 1.0f);      // erf(y), y>=0
      vs[k] = copysignf(er, dk[k]);
    }
  }

  // ---- phase 1: heaviside counts, nibble-packed ----
  const float lo = __uint_as_float(0xBF7FFFFFu);
  uint32_t cntP = 0;
  uint32_t cH = (uint32_t)P * 8u;
  #pragma unroll 1
  for (int s = 0; s < 4; ++s) {
    uint32_t fm = 0, dm = 0;
    #pragma unroll
    for (int k = 0; k < 8; ++k) {
      uint32_t o0, o1;
      tf2x32(kh0, kh1, 0u, cH + (uint32_t)k, o0, o1);
      uint32_t bits = o0 ^ o1;
      float f = __uint_as_float((bits >> 9) | 0x3f800000u) - 1.0f;
      float vapp = __fmaf_rn(f, 2.0f, lo);
      bool de = vapp >= vs[k];
      fm |= (fabsf(vapp - vs[k]) < BAND_H ? 1u : 0u) << k;
      dm |= (de ? 1u : 0u) << k;
      cntP += de ? (1u << (4 * k)) : 0u;
    }
    if (__builtin_expect(fm != 0u, 0)) {   // rare, exec-masked
      #pragma unroll 1
      for (int k = 0; k < 8; ++k) {
        if ((fm >> k) & 1u) {
          uint32_t o0, o1;
          tf2x32(kh0, kh1, 0u, cH + (uint32_t)k, o0, o1);
          float nz = normal_exact(o0 ^ o1);
          float x = -dists[(size_t)P * 8 + k];   // cold reload
          uint32_t ed = (__fadd_rn(x, __fmul_rn(0.1f, nz)) >= 0.0f) ? 1u : 0u;
          cntP += (ed - ((dm >> k) & 1u)) << (4 * k);  // mod-2^32 fixup
        }
      }
    }
    cH += STRIDE_H;
  }

  // ---- phase 2: alpha, z_inv, z_map (exact, round-4-validated) ----
  float zk[8];
  int mk[8];
  {
    const float4* z4 = reinterpret_cast<const float4*>(zbuf + (size_t)P * 8);
    float4 c = z4[0], e = z4[1];
    zk[0]=c.x; zk[1]=c.y; zk[2]=c.z; zk[3]=c.w; zk[4]=e.x; zk[5]=e.y; zk[6]=e.z; zk[7]=e.w;
    const int4* m4 = reinterpret_cast<const int4*>(p2f + (size_t)P * 8);
    int4 f = m4[0], g = m4[1];
    mk[0]=f.x; mk[1]=f.y; mk[2]=f.z; mk[3]=f.w; mk[4]=g.x; mk[5]=g.y; mk[6]=g.z; mk[7]=g.w;
  }
  float zinv[8], zmax;
  #pragma unroll
  for (int k = 0; k < 8; ++k) {
    const float m = (mk[k] >= 0) ? 1.0f : 0.0f;
    float zi = __fmul_rn(__fdiv_rn(__fsub_rn(100.0f, zk[k]), 99.0f), m);
    zinv[k] = zi;
    zmax = (k == 0) ? zi : fmaxf(zmax, zi);
  }
  zmax = fmaxf(zmax, 1e-10f);

  const float lg0 = (float)-23.025850916589025;  // log(1e-10f)
  const float lg1 = (float)-1.3862943611198906;  // log(0.25)
  const float lg2 = (float)-0.6931471805599453;  // log(0.5)
  const float lg3 = (float)-0.2876820724517809;  // log(0.75)

  float alpha = 1.0f;
  float zm[9];
  #pragma unroll
  for (int k = 0; k < 8; ++k) {
    const int cntk = (int)((cntP >> (4 * k)) & 15u);
    const float m = (mk[k] >= 0) ? 1.0f : 0.0f;
    const float pm = __fmul_rn(__fmul_rn((float)cntk, 0.25f), m);
    alpha *= (1.0f - pm);  // exact (short products of 2-bit-mantissa values)
    const int i = (mk[k] >= 0) ? cntk : 0;
    const float lg = (i == 0) ? lg0 : (i == 1) ? lg1 : (i == 2) ? lg2
                   : (i == 3) ? lg3 : 0.0f;
    zm[k] = __fadd_rn(lg, __fdiv_rn(__fsub_rn(zinv[k], zmax), 0.1f));
    zmS[tid][k] = zm[k];
  }
  zm[8] = __fdiv_rn(__fsub_rn(1e-10f, zmax), 0.1f);
  zmS[tid][8] = zm[8];

  // ---- phase 3: random_argmax (approx + banded fallback) ----
  uint32_t amPack = 0;
  uint32_t cA = (uint32_t)P * 9u;
  #pragma unroll 1
  for (int s = 0; s < 4; ++s) {
    int am = 0;
    float best = -3.4e38f;
    bool fl = false;
    #pragma unroll
    for (int j = 0; j < 9; ++j) {
      uint32_t o0, o1;
      tf2x32(ka0, ka1, 0u, cA + (uint32_t)j, o0, o1);
      float nz = normal_fast(o0 ^ o1);
      float vv = __fmaf_rn(0.1f, nz, zm[j]);
      fl |= fabsf(vv - best) < BAND_A;
      bool g = vv > best;
      best = g ? vv : best;
      am = g ? j : am;
    }
    if (__builtin_expect(__ballot(fl) != 0ull, 0)) {
      if (fl) {                        // exec-masked exact redo
        int ame = 0;
        float be = -3.4e38f;
        #pragma unroll 1
        for (int j = 0; j < 9; ++j) {
          uint32_t o0, o1;
          tf2x32(ka0, ka1, 0u, cA + (uint32_t)j, o0, o1);
          float nz = normal_exact(o0 ^ o1);
          float ve = __fadd_rn(zmS[tid][j], __fmul_rn(0.1f, nz));
          bool g = ve > be;
          be = g ? ve : be;
          ame = g ? j : ame;
        }
        am = ame;
      }
    }
    amPack += 1u << (3 * am);
    cA += STRIDE_A;
  }

  // ---- phase 4: epilogue ----
  float wgt[9];
  #pragma unroll
  for (int j = 0; j < 9; ++j)
    wgt[j] = __fmul_rn(0.25f, (float)((amPack >> (3 * j)) & 7u));  // exact

  float cc[24];
  {
    const float4* c4 = reinterpret_cast<const float4*>(colors + (size_t)P * 24);
    #pragma unroll
    for (int q = 0; q < 6; ++q) {
      float4 t = c4[q];
      cc[q*4+0]=t.x; cc[q*4+1]=t.y; cc[q*4+2]=t.z; cc[q*4+3]=t.w;
    }
  }
  float rgb[3];
  #pragma unroll
  for (int c = 0; c < 3; ++c) {
    float acc = 0.0f;
    #pragma unroll
    for (int k = 0; k < 8; ++k)
      acc = __fadd_rn(acc, __fmul_rn(wgt[k], cc[k * 3 + c]));
    rgb[c] = __fadd_rn(acc, __fmul_rn(wgt[8], bg[c]));
  }

  float4 o;
  o.x = rgb[0]; o.y = rgb[1]; o.z = rgb[2];
  o.w = __fsub_rn(1.0f, alpha);
  reinterpret_cast<float4*>(out)[P] = o;
}

extern "C" void kernel_launch(void* const* d_in, const int* in_sizes, int n_in,
                              void* d_out, int out_size, void* d_ws, size_t ws_size,
                              hipStream_t stream) {
  const float* colors = (const float*)d_in[0];
  const float* dists  = (const float*)d_in[1];
  const float* zbuf   = (const float*)d_in[2];
  const int*   p2f    = (const int*)d_in[3];
  const float* bg     = (const float*)d_in[4];
  float* out = (float*)d_out;
  dim3 grid(NPIX / 256), block(256);
  hipLaunchKernelGGL(RandomPhongShader_kernel, grid, block, 0, stream,
                     colors, dists, zbuf, p2f, bg, out);
}